// Round 15
// baseline (236.988 us; speedup 1.0000x reference)
//
#include <hip/hip_runtime.h>
#include <hip/hip_bf16.h>

// Problem constants: B=4, T=2048, C=1024, NH=16, HD=64
#define TSEQ   2048
#define CDIM   1024
#define NHEAD  16
#define HDIM   64

typedef float f32x4  __attribute__((ext_vector_type(4)));
typedef float f32x16v __attribute__((ext_vector_type(16)));
typedef __bf16 bf16x8 __attribute__((ext_vector_type(8)));
typedef unsigned short u16x8 __attribute__((ext_vector_type(8)));
typedef unsigned short u16x4 __attribute__((ext_vector_type(4)));
typedef unsigned int   u32x4 __attribute__((ext_vector_type(4)));

#define QSCALE 0.18033688011112042f   // 0.125 * log2(e)
#define LOG2E  1.4426950408889634f

static __device__ __forceinline__ unsigned short f2bf(float f) {
    unsigned u = __builtin_bit_cast(unsigned, f);
    unsigned r = u + 0x7FFFu + ((u >> 16) & 1u);   // round-to-nearest-even
    return (unsigned short)(r >> 16);
}
static __device__ __forceinline__ float bf2f(unsigned short u) {
    unsigned v = ((unsigned)u) << 16;
    return __builtin_bit_cast(float, v);
}

static __device__ __forceinline__ f32x4 mfma16(u16x8 a, u16x8 b, f32x4 c) {
    return __builtin_amdgcn_mfma_f32_16x16x32_bf16(
        __builtin_bit_cast(bf16x8, a), __builtin_bit_cast(bf16x8, b), c, 0, 0, 0);
}
static __device__ __forceinline__ f32x16v mfma32(u16x8 a, u16x8 b, f32x16v c) {
    return __builtin_amdgcn_mfma_f32_32x32x16_bf16(
        __builtin_bit_cast(bf16x8, a), __builtin_bit_cast(bf16x8, b), c, 0, 0, 0);
}

static __device__ __forceinline__ void gload16(const void* g, void* l) {
    __builtin_amdgcn_global_load_lds(
        (const __attribute__((address_space(1))) unsigned int*)g,
        (__attribute__((address_space(3))) unsigned int*)l, 16, 0, 0);
}

// Workspace layout (u16 units):
//   wb   : 0        .. 4194303   (W^T q,k,v,o bf16, 1M each -- TRANSPOSED [n][k])
//   xb   : 4194304  .. 12582911  (x bf16, 8M) -- reused as `ao` after QKV GEMM
//   qh   : 12582912 .. 20971519  ([B,NH,T,HD] bf16, pre-scaled by QSCALE)
//   kh   : 20971520 .. 29359103  ([B,NH,T,HD] bf16)
//   vt   : 29359104 .. 37748735  ([B,NH,HD,T] bf16 -- V TRANSPOSED)
//   part : 37748736 .. 41943039  (256 slots x 256x64 bf16 seg0 O-partials)
//   mlb  : 41943040 .. 42467327  (256 x 2seg x 256 x 2 f32)  -- total 84.9 MB

// ---------------------------------------------------------------------------
__global__ __launch_bounds__(256) void castx(
    const float* __restrict__ x, unsigned short* __restrict__ xb)
{
    int t = blockIdx.x * 256 + threadIdx.x;   // float4 index, < 2097152
    f32x4 v = *(const f32x4*)&x[t * 4];
    u16x4 o;
    o[0] = f2bf(v[0]); o[1] = f2bf(v[1]); o[2] = f2bf(v[2]); o[3] = f2bf(v[3]);
    *(u16x4*)&xb[t * 4] = o;
}

// ---------------------------------------------------------------------------
__global__ __launch_bounds__(256) void wtcast(
    const float* __restrict__ wq, const float* __restrict__ wk,
    const float* __restrict__ wv, const float* __restrict__ wo,
    unsigned short* __restrict__ wt)
{
    __shared__ unsigned short t[64 * 72];
    const int z = blockIdx.z;
    const float* src = (z == 0) ? wq : (z == 1) ? wk : (z == 2) ? wv : wo;
    const int k0 = blockIdx.x * 64, n0 = blockIdx.y * 64, tid = threadIdx.x;

    #pragma unroll
    for (int i = 0; i < 4; ++i) {
        int idx = i * 256 + tid;
        int r = idx >> 4, c4 = idx & 15;
        f32x4 v = *(const f32x4*)&src[(k0 + r) * 1024 + n0 + c4 * 4];
        u16x4 o;
        o[0] = f2bf(v[0]); o[1] = f2bf(v[1]); o[2] = f2bf(v[2]); o[3] = f2bf(v[3]);
        *(u16x4*)&t[r * 72 + c4 * 4] = o;
    }
    __syncthreads();
    #pragma unroll
    for (int i = 0; i < 2; ++i) {
        int idx = i * 256 + tid;
        int n = idx >> 3, k8 = idx & 7;
        u16x8 o;
        #pragma unroll
        for (int e = 0; e < 8; ++e) o[e] = t[(k8 * 8 + e) * 72 + n];
        *(u16x8*)&wt[z * 1048576 + (n0 + n) * 1024 + k0 + k8 * 8] = o;
    }
}

// ---------------------------------------------------------------------------
template<int MODE>
__global__ __launch_bounds__(256) void gemm_gl(
    const unsigned short* __restrict__ A, const unsigned short* __restrict__ WT,
    unsigned short* __restrict__ outb, float* __restrict__ outf)
{
    __shared__ __align__(16) unsigned short Al[128 * 64];
    __shared__ __align__(16) unsigned short Bl[128 * 64];

    const int tid  = threadIdx.x;
    const int z    = blockIdx.z;
    const int m0   = blockIdx.y * 128;
    const int n0   = blockIdx.x * 128;
    const unsigned short* W = WT + (MODE == 0 ? z * 1048576 : 0);

    const int wid  = tid >> 6, lane = tid & 63;
    const int wr   = (wid >> 1) * 64, wc = (wid & 1) * 64;
    const int lrow = lane & 15, lk = (lane >> 4) * 8;

    f32x4 acc[4][4] = {};

    for (int kt = 0; kt < 16; ++kt) {
        __syncthreads();
        #pragma unroll
        for (int c = 0; c < 4; ++c) {
            int cz = wid * 4 + c;
            int row = cz * 8 + (lane >> 3), col = (lane & 7) * 8;
            gload16(&A[(m0 + row) * 1024 + kt * 64 + col], &Al[cz * 512]);
            gload16(&W[(n0 + row) * 1024 + kt * 64 + col], &Bl[cz * 512]);
        }
        __syncthreads();
        #pragma unroll
        for (int ks = 0; ks < 2; ++ks) {
            u16x8 af[4], bfr[4];
            #pragma unroll
            for (int m = 0; m < 4; ++m)
                af[m] = *(const u16x8*)&Al[(wr + m * 16 + lrow) * 64 + ks * 32 + lk];
            #pragma unroll
            for (int n = 0; n < 4; ++n)
                bfr[n] = *(const u16x8*)&Bl[(wc + n * 16 + lrow) * 64 + ks * 32 + lk];
            #pragma unroll
            for (int m = 0; m < 4; ++m)
                #pragma unroll
                for (int n = 0; n < 4; ++n)
                    acc[m][n] = mfma16(af[m], bfr[n], acc[m][n]);
        }
    }

    const int g = lane >> 4;
    #pragma unroll
    for (int m = 0; m < 4; ++m)
        #pragma unroll
        for (int n = 0; n < 4; ++n)
            #pragma unroll
            for (int j = 0; j < 4; ++j) {
                int grow = m0 + wr + m * 16 + g * 4 + j;
                int gcol = n0 + wc + n * 16 + lrow;
                float val = acc[m][n][j];
                if (MODE == 0) {
                    int b = grow >> 11, t = grow & 2047;
                    int h = gcol >> 6,  d = gcol & 63;
                    if (z == 0) val *= QSCALE;
                    if (z == 2)
                        outb[z * 8388608 + (((b << 4) + h) * 64 + d) * 2048 + t] = f2bf(val);
                    else
                        outb[z * 8388608 + (((b << 4) + h) * 2048 + t) * 64 + d] = f2bf(val);
                } else {
                    outf[grow * 1024 + gcol] = val;
                }
            }
}

// ---------------------------------------------------------------------------
// Kernel 3: uniform split-KV 8-wave flash attention. Block (j=x>>1, seg=x&1,
// bh): seg0 = chunk cA=7-j tiles [t0A..8] -> bf16 O-partial in `part` + (m,l);
// seg1 = chunk cA tiles [max(9,t0A)..2cA+1] -> unnormalized O to ao + (m,l),
// THEN chunk cB=j full chain -> normalized ao. Full-causal lengths 9 & 9 ->
// 512 uniform blocks = exactly 2/CU (64KB LDS, VGPR<=128), all resident,
// no queueing; makespan = 9 tiles. combine2 merges chunk-A partials.
// Body identical to r14 (XOR-swizzled global_load_lds, swapped QK^T 32x32,
// raw-max bound, fused bias-exp2, defer-max, nkv2 diag skip, window gates).
// ---------------------------------------------------------------------------
__global__ __launch_bounds__(512, 2) void attnsp(
    const unsigned short* __restrict__ qh, const unsigned short* __restrict__ kh,
    const unsigned short* __restrict__ vt, unsigned short* __restrict__ part,
    float* __restrict__ mlb, unsigned short* __restrict__ aout)
{
    __shared__ __align__(16) unsigned short Kl[2][128 * 64];
    __shared__ __align__(16) unsigned short Vl[2][64 * 128];

    const int j   = blockIdx.x >> 1, seg = blockIdx.x & 1;
    const int bh  = blockIdx.y;
    const int h   = bh & 15, b = bh >> 4;
    const int cA  = 7 - j, cB = j;
    const int slot = bh * 4 + (cA - 4);    // 0..255
    const int tid = threadIdx.x, wid = tid >> 6, lane = tid & 63;
    const int l31 = lane & 31, hi = lane >> 5;

    const unsigned short* Qb = qh + bh * (TSEQ * HDIM);
    const unsigned short* Kb = kh + bh * (TSEQ * HDIM);
    const unsigned short* Vb = vt + bh * (TSEQ * HDIM);  // [d][t]

    const float slope2 = exp2f(-0.5f * (float)(h + 1)) * LOG2E;
    const int   Wwin   = (int)ceilf(40.0f / slope2);     // ALiBi window

    int a0 = cA * 256 - Wwin; const int t0A = (a0 > 0) ? (a0 >> 7) : 0;
    int b0 = cB * 256 - Wwin; const int t0B = (b0 > 0) ? (b0 >> 7) : 0;
    const int nphase = seg ? 2 : 1;

    // staging lane constants (source-side XOR swizzle, LDS dest linear)
    const int krow = lane >> 3;
    const int kgc  = (lane & 7) ^ krow;
    const int vrow = lane >> 4;
    const int vcc  = lane & 15;

#define STAGE(BUF, KV) do {                                                   \
    _Pragma("unroll")                                                         \
    for (int i_ = 0; i_ < 2; ++i_) {                                          \
        int cz_ = wid * 2 + i_;                       /* 0..15 */             \
        gload16(&Kb[((KV) + cz_ * 8 + krow) * 64 + kgc * 8],                  \
                &Kl[BUF][cz_ * 512]);                                         \
        int d_ = cz_ * 4 + vrow;                                              \
        int gc_ = vcc ^ (d_ & 15);                                            \
        gload16(&Vb[d_ * 2048 + (KV) + gc_ * 8], &Vl[BUF][cz_ * 512]);        \
    } } while (0)

    for (int ph = 0; ph < nphase; ++ph) {
        const int c   = ph ? cB : cA;
        const int tlo = ph ? t0B : (seg ? ((t0A > 9) ? t0A : 9) : t0A);
        const int thi = ph ? (2 * cB + 1) : (seg ? (2 * cA + 1) : 8);

        const int qw = c * 256 + wid * 32;
        const int qg = qw + l31;
        u16x8 qf[4];
        #pragma unroll
        for (int kf = 0; kf < 4; ++kf)
            qf[kf] = *(const u16x8*)&Qb[qg * 64 + kf * 16 + hi * 8];
        float m_r = -1e30f, l_r = 0.f;
        f32x16v Ot[2] = {};                // O^T: d = dn*32+(r&3)+8*(r>>2)+4*hi

        __syncthreads();                   // protect LDS across phases
        if (tlo <= thi) {
            STAGE(0, tlo * 128);
            int cur = 0;
            for (int t = tlo; t <= thi; ++t) {
                const int kv0 = t * 128;
                __syncthreads();           // drains this tile's loads

                if (t < thi) STAGE(cur ^ 1, (t + 1) * 128);

                if (kv0 <= qw + 31 && kv0 + 127 >= qw - Wwin) {
                    const int v0 = qw - kv0;   // >= 0 when gate passes & t<=diag
                    int nkv2 = (v0 >> 5) + 1;
                    if (nkv2 > 4) nkv2 = 4;
                    if (nkv2 < 1) nkv2 = 1;
                    const bool diag = (kv0 + 127 > qw);

                    f32x16v st[4];
                    __builtin_amdgcn_s_setprio(1);
                    #pragma unroll
                    for (int kv2 = 0; kv2 < 4; ++kv2) {
                        if (kv2 < nkv2) {
                            f32x16v a = {};
                            #pragma unroll
                            for (int kf = 0; kf < 4; ++kf) {
                                u16x8 ka = *(const u16x8*)&Kl[cur][(kv2 * 32 + l31) * 64 +
                                                                   (((kf * 2 + hi) ^ (l31 & 7)) * 8)];
                                a = mfma32(ka, qf[kf], a);
                            }
                            st[kv2] = a;
                        } else {
                            st[kv2] = (f32x16v)(-1e30f);
                        }
                    }
                    __builtin_amdgcn_s_setprio(0);

                    if (diag) {
                        #pragma unroll
                        for (int kv2 = 0; kv2 < 4; ++kv2) {
                            if (kv2 < nkv2) {
                                #pragma unroll
                                for (int r = 0; r < 16; ++r) {
                                    int kv = kv0 + kv2 * 32 + (r & 3) + 8 * (r >> 2) + 4 * hi;
                                    if (kv > qg) st[kv2][r] = -1e30f;
                                }
                            }
                        }
                    }

                    float t16[16];
                    #pragma unroll
                    for (int i = 0; i < 16; ++i)
                        t16[i] = fmaxf(fmaxf(st[0][i], st[1][i]), fmaxf(st[2][i], st[3][i]));
                    #pragma unroll
                    for (int i = 0; i < 8; ++i) t16[i] = fmaxf(t16[i], t16[i + 8]);
                    #pragma unroll
                    for (int i = 0; i < 4; ++i) t16[i] = fmaxf(t16[i], t16[i + 4]);
                    float rm = fmaxf(fmaxf(t16[0], t16[1]), fmaxf(t16[2], t16[3]));
                    rm = fmaxf(rm, __shfl_xor(rm, 32, 64));

                    int kvmax = kv0 + 127; if (kvmax > qw + 31) kvmax = qw + 31;
                    float cand = rm + slope2 * (float)(kvmax - 2047);

                    if (!__all(cand - m_r <= 8.0f)) {
                        float mn = fmaxf(m_r, cand);
                        float alpha = exp2f(m_r - mn);
                        m_r = mn;
                        l_r *= alpha;
                        Ot[0] *= alpha;
                        Ot[1] *= alpha;
                    }

                    unsigned pku[4][8];
                    float s16[16] = {};
                    #pragma unroll
                    for (int kv2 = 0; kv2 < 4; ++kv2) {
                        if (kv2 < nkv2) {
                            float base2 = slope2 * (float)(kv0 + kv2 * 32 + 4 * hi - 2047) - m_r;
                            #pragma unroll
                            for (int r = 0; r < 16; ++r) {
                                float koff = (float)((r & 3) + 8 * (r >> 2));
                                st[kv2][r] = exp2f(st[kv2][r] + fmaf(slope2, koff, base2));
                                s16[r] += st[kv2][r];
                            }
                            #pragma unroll
                            for (int idx = 0; idx < 8; ++idx) {
                                unsigned lo2 = __builtin_bit_cast(unsigned short, (__bf16)st[kv2][2 * idx]);
                                unsigned hh = __builtin_bit_cast(unsigned short, (__bf16)st[kv2][2 * idx + 1]);
                                pku[kv2][idx] = lo2 | (hh << 16);
                            }
                        }
                    }
                    #pragma unroll
                    for (int i = 0; i < 8; ++i) s16[i] += s16[i + 8];
                    #pragma unroll
                    for (int i = 0; i < 4; ++i) s16[i] += s16[i + 4];
                    float rs = (s16[0] + s16[1]) + (s16[2] + s16[3]);
                    rs += __shfl_xor(rs, 32, 64);
                    l_r += rs;

                    __builtin_amdgcn_s_setprio(1);
                    #pragma unroll
                    for (int kf = 0; kf < 8; ++kf) {
                        if ((kf >> 1) < nkv2) {
                            const int kv2 = kf >> 1, base = 4 * (kf & 1);
                            unsigned s0 = hi ? pku[kv2][base + 0] : pku[kv2][base + 2];
                            unsigned s1 = hi ? pku[kv2][base + 1] : pku[kv2][base + 3];
                            unsigned r0 = __shfl_xor(s0, 32, 64);
                            unsigned r1 = __shfl_xor(s1, 32, 64);
                            u32x4 w;
                            w[0] = hi ? r0 : pku[kv2][base + 0];
                            w[1] = hi ? r1 : pku[kv2][base + 1];
                            w[2] = hi ? pku[kv2][base + 2] : r0;
                            w[3] = hi ? pku[kv2][base + 3] : r1;
                            u16x8 pb = __builtin_bit_cast(u16x8, w);
                            #pragma unroll
                            for (int dn = 0; dn < 2; ++dn) {
                                u16x8 va = *(const u16x8*)&Vl[cur][(dn * 32 + l31) * 128 +
                                                                   (((kf * 2 + hi) ^ (l31 & 15)) * 8)];
                                Ot[dn] = mfma32(va, pb, Ot[dn]);
                            }
                        }
                    }
                    __builtin_amdgcn_s_setprio(0);
                }

                cur ^= 1;
            }
        }

        // per-phase output
        const int qloc = wid * 32 + l31;   // 0..255 within chunk
        if (ph == 0 && seg == 0) {
            // chunk-A seg0 partial -> part + mlb (zeros if range empty)
            unsigned short* P = part + slot * 16384;
            #pragma unroll
            for (int dn = 0; dn < 2; ++dn)
                #pragma unroll
                for (int rq = 0; rq < 4; ++rq) {
                    u16x4 o;
                    #pragma unroll
                    for (int jj = 0; jj < 4; ++jj)
                        o[jj] = f2bf(Ot[dn][rq * 4 + jj]);
                    int d = dn * 32 + 8 * rq + 4 * hi;
                    *(u16x4*)&P[qloc * 64 + d] = o;
                }
            mlb[(slot * 2 + 0) * 512 + qloc * 2 + 0] = m_r;
            mlb[(slot * 2 + 0) * 512 + qloc * 2 + 1] = l_r;
        } else if (ph == 0) {
            // chunk-A seg1 partial -> ao UNNORMALIZED + mlb
            #pragma unroll
            for (int dn = 0; dn < 2; ++dn)
                #pragma unroll
                for (int rq = 0; rq < 4; ++rq) {
                    u16x4 o;
                    #pragma unroll
                    for (int jj = 0; jj < 4; ++jj)
                        o[jj] = f2bf(Ot[dn][rq * 4 + jj]);
                    int d = dn * 32 + 8 * rq + 4 * hi;
                    *(u16x4*)&aout[(b * 2048 + qg) * 1024 + h * 64 + d] = o;
                }
            mlb[(slot * 2 + 1) * 512 + qloc * 2 + 0] = m_r;
            mlb[(slot * 2 + 1) * 512 + qloc * 2 + 1] = l_r;
        } else {
            // chunk-B full result -> ao normalized
            float rl = 1.0f / l_r;
            #pragma unroll
            for (int dn = 0; dn < 2; ++dn)
                #pragma unroll
                for (int rq = 0; rq < 4; ++rq) {
                    u16x4 o;
                    #pragma unroll
                    for (int jj = 0; jj < 4; ++jj)
                        o[jj] = f2bf(Ot[dn][rq * 4 + jj] * rl);
                    int d = dn * 32 + 8 * rq + 4 * hi;
                    *(u16x4*)&aout[(b * 2048 + qg) * 1024 + h * 64 + d] = o;
                }
        }
    }
#undef STAGE
}

// ---------------------------------------------------------------------------
// Kernel 3b: merge chunk-A partials: O = (O0*w0 + O1*w1)/(l0*w0 + l1*w1).
// O0 = part (seg0), O1 = ao rows (seg1, unnormalized). Grid (4, 64) x 256.
// ---------------------------------------------------------------------------
__global__ __launch_bounds__(256) void combine2(
    const unsigned short* __restrict__ part, const float* __restrict__ mlb,
    unsigned short* __restrict__ aout)
{
    const int cx = blockIdx.x;             // cA = 4 + cx
    const int bh = blockIdx.y;
    const int h  = bh & 15, b = bh >> 4;
    const int slot = bh * 4 + cx;
    const int q  = threadIdx.x;            // 0..255

    float m0 = mlb[(slot * 2 + 0) * 512 + q * 2 + 0];
    float l0 = mlb[(slot * 2 + 0) * 512 + q * 2 + 1];
    float m1 = mlb[(slot * 2 + 1) * 512 + q * 2 + 0];
    float l1 = mlb[(slot * 2 + 1) * 512 + q * 2 + 1];
    float M  = fmaxf(m0, m1);
    float w0 = exp2f(m0 - M), w1 = exp2f(m1 - M);
    float rl = 1.0f / (l0 * w0 + l1 * w1);

    const unsigned short* P0 = part + slot * 16384 + q * 64;
    unsigned short* dst = aout + ((b * 2048 + (4 + cx) * 256 + q) * 1024 + h * 64);

    #pragma unroll
    for (int i = 0; i < 8; ++i) {
        u16x8 a0 = *(const u16x8*)&P0[i * 8];
        u16x8 a1 = *(const u16x8*)&dst[i * 8];
        u16x8 o;
        #pragma unroll
        for (int e = 0; e < 8; ++e)
            o[e] = f2bf((bf2f(a0[e]) * w0 + bf2f(a1[e]) * w1) * rl);
        *(u16x8*)&dst[i * 8] = o;
    }
}

// ---------------------------------------------------------------------------
extern "C" void kernel_launch(void* const* d_in, const int* in_sizes, int n_in,
                              void* d_out, int out_size, void* d_ws, size_t ws_size,
                              hipStream_t stream)
{
    const float* x  = (const float*)d_in[0];
    const float* Wq = (const float*)d_in[1];
    const float* Wk = (const float*)d_in[2];
    const float* Wv = (const float*)d_in[3];
    const float* Wo = (const float*)d_in[4];

    unsigned short* ws = (unsigned short*)d_ws;
    unsigned short* wb = ws;                       // 4 x 1M bf16 (W^T: q,k,v,o)
    unsigned short* xb = ws + 4194304;             // 8M bf16
    unsigned short* qh = ws + 12582912;
    unsigned short* kh = qh + 8388608;
    unsigned short* vt = kh + 8388608;
    unsigned short* part = ws + 37748736;          // 256 x 16384 u16
    float* mlb = (float*)(ws + 41943040);          // 256 x 2 x 512 f32
    unsigned short* ao = xb;                       // alias: xb dead after QKV GEMM

    castx<<<dim3(8192), dim3(256), 0, stream>>>(x, xb);
    wtcast<<<dim3(16, 16, 4), dim3(256), 0, stream>>>(Wq, Wk, Wv, Wo, wb);
    gemm_gl<0><<<dim3(8, 64, 3), dim3(256), 0, stream>>>(xb, wb, qh, (float*)nullptr);
    attnsp<<<dim3(8, 64), dim3(512), 0, stream>>>(qh, kh, vt, part, mlb, ao);
    combine2<<<dim3(4, 64), dim3(256), 0, stream>>>(part, mlb, ao);
    gemm_gl<1><<<dim3(8, 64, 1), dim3(256), 0, stream>>>(
        ao, wb + 3 * 1048576, (unsigned short*)nullptr, (float*)d_out);
}

// Round 16
// 230.342 us; speedup vs baseline: 1.0289x; 1.0289x over previous
//
#include <hip/hip_runtime.h>
#include <hip/hip_bf16.h>

// Problem constants: B=4, T=2048, C=1024, NH=16, HD=64
#define TSEQ   2048
#define CDIM   1024
#define NHEAD  16
#define HDIM   64

typedef float f32x4  __attribute__((ext_vector_type(4)));
typedef float f32x16v __attribute__((ext_vector_type(16)));
typedef __bf16 bf16x8 __attribute__((ext_vector_type(8)));
typedef unsigned short u16x8 __attribute__((ext_vector_type(8)));
typedef unsigned short u16x4 __attribute__((ext_vector_type(4)));
typedef unsigned int   u32x4 __attribute__((ext_vector_type(4)));

#define QSCALE 0.18033688011112042f   // 0.125 * log2(e)
#define LOG2E  1.4426950408889634f

static __device__ __forceinline__ unsigned short f2bf(float f) {
    unsigned u = __builtin_bit_cast(unsigned, f);
    unsigned r = u + 0x7FFFu + ((u >> 16) & 1u);   // round-to-nearest-even
    return (unsigned short)(r >> 16);
}

static __device__ __forceinline__ f32x4 mfma16(u16x8 a, u16x8 b, f32x4 c) {
    return __builtin_amdgcn_mfma_f32_16x16x32_bf16(
        __builtin_bit_cast(bf16x8, a), __builtin_bit_cast(bf16x8, b), c, 0, 0, 0);
}
static __device__ __forceinline__ f32x16v mfma32(u16x8 a, u16x8 b, f32x16v c) {
    return __builtin_amdgcn_mfma_f32_32x32x16_bf16(
        __builtin_bit_cast(bf16x8, a), __builtin_bit_cast(bf16x8, b), c, 0, 0, 0);
}

static __device__ __forceinline__ void gload16(const void* g, void* l) {
    __builtin_amdgcn_global_load_lds(
        (const __attribute__((address_space(1))) unsigned int*)g,
        (__attribute__((address_space(3))) unsigned int*)l, 16, 0, 0);
}

// Workspace layout (u16 units):
//   wb : 0        .. 4194303   (W^T q,k,v,o bf16, 1M each -- TRANSPOSED [n][k])
//   xb : 4194304  .. 12582911  (x bf16, 8M) -- reused as `ao` after QKV GEMM
//   qh : 12582912 .. 20971519  ([B,NH,T,HD] bf16, pre-scaled by QSCALE)
//   kh : 20971520 .. 29359103  ([B,NH,T,HD] bf16)
//   vt : 29359104 .. 37748735  ([B,NH,HD,T] bf16 -- V TRANSPOSED)

// ---------------------------------------------------------------------------
__global__ __launch_bounds__(256) void castx(
    const float* __restrict__ x, unsigned short* __restrict__ xb)
{
    int t = blockIdx.x * 256 + threadIdx.x;   // float4 index, < 2097152
    f32x4 v = *(const f32x4*)&x[t * 4];
    u16x4 o;
    o[0] = f2bf(v[0]); o[1] = f2bf(v[1]); o[2] = f2bf(v[2]); o[3] = f2bf(v[3]);
    *(u16x4*)&xb[t * 4] = o;
}

// ---------------------------------------------------------------------------
__global__ __launch_bounds__(256) void wtcast(
    const float* __restrict__ wq, const float* __restrict__ wk,
    const float* __restrict__ wv, const float* __restrict__ wo,
    unsigned short* __restrict__ wt)
{
    __shared__ unsigned short t[64 * 72];
    const int z = blockIdx.z;
    const float* src = (z == 0) ? wq : (z == 1) ? wk : (z == 2) ? wv : wo;
    const int k0 = blockIdx.x * 64, n0 = blockIdx.y * 64, tid = threadIdx.x;

    #pragma unroll
    for (int i = 0; i < 4; ++i) {
        int idx = i * 256 + tid;
        int r = idx >> 4, c4 = idx & 15;
        f32x4 v = *(const f32x4*)&src[(k0 + r) * 1024 + n0 + c4 * 4];
        u16x4 o;
        o[0] = f2bf(v[0]); o[1] = f2bf(v[1]); o[2] = f2bf(v[2]); o[3] = f2bf(v[3]);
        *(u16x4*)&t[r * 72 + c4 * 4] = o;
    }
    __syncthreads();
    #pragma unroll
    for (int i = 0; i < 2; ++i) {
        int idx = i * 256 + tid;
        int n = idx >> 3, k8 = idx & 7;
        u16x8 o;
        #pragma unroll
        for (int e = 0; e < 8; ++e) o[e] = t[(k8 * 8 + e) * 72 + n];
        *(u16x8*)&wt[z * 1048576 + (n0 + n) * 1024 + k0 + k8 * 8] = o;
    }
}

// ---------------------------------------------------------------------------
// Kernel 2/4: 128x128 bf16 GEMM, BK=64, global_load_lds staging, with
// XCD-aware bijective block swizzle (T1): in-plane bid = y*8+x (dispatch
// order, x fastest); nb = (bid%8)*64 + bid/8 gives each XCD a contiguous
// 64-tile chunk = 8 m-panels x all 8 n-panels -> working set 2MB A + 2MB W
// fits one 4MB per-XCD L2 (512%8==0 -> bijective).
// MODE 0: z = q/k/v. q scaled by QSCALE; v written transposed [bh][d][t].
// MODE 1: fp32 row-major to d_out.
// ---------------------------------------------------------------------------
template<int MODE>
__global__ __launch_bounds__(256) void gemm_gl(
    const unsigned short* __restrict__ A, const unsigned short* __restrict__ WT,
    unsigned short* __restrict__ outb, float* __restrict__ outf)
{
    __shared__ __align__(16) unsigned short Al[128 * 64];
    __shared__ __align__(16) unsigned short Bl[128 * 64];

    const int tid  = threadIdx.x;
    const int z    = blockIdx.z;
    const int bidp = blockIdx.y * 8 + blockIdx.x;        // 0..511 in-plane
    const int nb   = (bidp & 7) * 64 + (bidp >> 3);      // XCD-chunked remap
    const int m0   = (nb >> 3) * 128;
    const int n0   = (nb & 7) * 128;
    const unsigned short* W = WT + (MODE == 0 ? z * 1048576 : 0);

    const int wid  = tid >> 6, lane = tid & 63;
    const int wr   = (wid >> 1) * 64, wc = (wid & 1) * 64;
    const int lrow = lane & 15, lk = (lane >> 4) * 8;

    f32x4 acc[4][4] = {};

    for (int kt = 0; kt < 16; ++kt) {
        __syncthreads();
        #pragma unroll
        for (int c = 0; c < 4; ++c) {
            int cz = wid * 4 + c;
            int row = cz * 8 + (lane >> 3), col = (lane & 7) * 8;
            gload16(&A[(m0 + row) * 1024 + kt * 64 + col], &Al[cz * 512]);
            gload16(&W[(n0 + row) * 1024 + kt * 64 + col], &Bl[cz * 512]);
        }
        __syncthreads();
        #pragma unroll
        for (int ks = 0; ks < 2; ++ks) {
            u16x8 af[4], bfr[4];
            #pragma unroll
            for (int m = 0; m < 4; ++m)
                af[m] = *(const u16x8*)&Al[(wr + m * 16 + lrow) * 64 + ks * 32 + lk];
            #pragma unroll
            for (int n = 0; n < 4; ++n)
                bfr[n] = *(const u16x8*)&Bl[(wc + n * 16 + lrow) * 64 + ks * 32 + lk];
            #pragma unroll
            for (int m = 0; m < 4; ++m)
                #pragma unroll
                for (int n = 0; n < 4; ++n)
                    acc[m][n] = mfma16(af[m], bfr[n], acc[m][n]);
        }
    }

    const int g = lane >> 4;
    #pragma unroll
    for (int m = 0; m < 4; ++m)
        #pragma unroll
        for (int n = 0; n < 4; ++n)
            #pragma unroll
            for (int j = 0; j < 4; ++j) {
                int grow = m0 + wr + m * 16 + g * 4 + j;
                int gcol = n0 + wc + n * 16 + lrow;
                float val = acc[m][n][j];
                if (MODE == 0) {
                    int b = grow >> 11, t = grow & 2047;
                    int h = gcol >> 6,  d = gcol & 63;
                    if (z == 0) val *= QSCALE;
                    if (z == 2)
                        outb[z * 8388608 + (((b << 4) + h) * 64 + d) * 2048 + t] = f2bf(val);
                    else
                        outb[z * 8388608 + (((b << 4) + h) * 2048 + t) * 64 + d] = f2bf(val);
                } else {
                    outf[grow * 1024 + gcol] = val;
                }
            }
}

// ---------------------------------------------------------------------------
// Kernel 3: 8-wave single-chunk flash attention (r14 best config, verbatim).
// Grid (8,64) = 512 blocks; c = (bh<32 ? 7-x : x). KVBLK=128 dbuf (64KB LDS),
// XOR-swizzled global_load_lds, swapped QK^T 32x32, raw-max bound, fused
// bias-exp2, defer-max, nkv2 diag skip, per-wave ALiBi window gates,
// windowed staging start. launch_bounds(512,2) caps VGPR at 128.
// ---------------------------------------------------------------------------
__global__ __launch_bounds__(512, 2) void attn8s(
    const unsigned short* __restrict__ qh, const unsigned short* __restrict__ kh,
    const unsigned short* __restrict__ vt, unsigned short* __restrict__ aout)
{
    __shared__ __align__(16) unsigned short Kl[2][128 * 64];
    __shared__ __align__(16) unsigned short Vl[2][64 * 128];

    const int bh  = blockIdx.y;
    const int h   = bh & 15, b = bh >> 4;
    const int c   = (bh < 32) ? (7 - (int)blockIdx.x) : (int)blockIdx.x;
    const int tid = threadIdx.x, wid = tid >> 6, lane = tid & 63;
    const int l31 = lane & 31, hi = lane >> 5;

    const unsigned short* Qb = qh + bh * (TSEQ * HDIM);
    const unsigned short* Kb = kh + bh * (TSEQ * HDIM);
    const unsigned short* Vb = vt + bh * (TSEQ * HDIM);  // [d][t]

    const float slope2 = exp2f(-0.5f * (float)(h + 1)) * LOG2E;
    const int   Wwin   = (int)ceilf(40.0f / slope2);     // ALiBi window

    // block tile range: windowed start .. diagonal tile of top wave
    int blo = c * 256 - Wwin;
    const int t0     = (blo > 0) ? (blo >> 7) : 0;
    const int t_last = 2 * c + 1;

    const int qw = c * 256 + wid * 32;     // wave's first q row
    const int qg = qw + l31;               // lane's q row

    // staging lane constants (source-side XOR swizzle, LDS dest linear)
    const int krow = lane >> 3;            // K: row within 8-row chunk
    const int kgc  = (lane & 7) ^ krow;    // K: swizzled 16B chunk
    const int vrow = lane >> 4;            // V: d-row within 4-row chunk
    const int vcc  = lane & 15;

#define STAGE(BUF, KV) do {                                                   \
    _Pragma("unroll")                                                         \
    for (int i_ = 0; i_ < 2; ++i_) {                                          \
        int cz_ = wid * 2 + i_;                       /* 0..15 */             \
        gload16(&Kb[((KV) + cz_ * 8 + krow) * 64 + kgc * 8],                  \
                &Kl[BUF][cz_ * 512]);                                         \
        int d_ = cz_ * 4 + vrow;                                              \
        int gc_ = vcc ^ (d_ & 15);                                            \
        gload16(&Vb[d_ * 2048 + (KV) + gc_ * 8], &Vl[BUF][cz_ * 512]);        \
    } } while (0)

    // Q B-frags: col = l31 -> q row, k = kf*16 + hi*8 + i (pre-scaled)
    u16x8 qf[4];
    #pragma unroll
    for (int kf = 0; kf < 4; ++kf)
        qf[kf] = *(const u16x8*)&Qb[qg * 64 + kf * 16 + hi * 8];
    float m_r = -1e30f, l_r = 0.f;
    f32x16v Ot[2] = {};                    // O^T: d = dn*32+(r&3)+8*(r>>2)+4*hi

    STAGE(0, t0 * 128);                    // prologue
    int cur = 0;

    for (int t = t0; t <= t_last; ++t) {
        const int kv0 = t * 128;
        __syncthreads();                   // drains this tile's loads

        if (t < t_last) STAGE(cur ^ 1, (t + 1) * 128);

        // wave-level gates: causal top + ALiBi window bottom
        if (kv0 <= qw + 31 && kv0 + 127 >= qw - Wwin) {
            const int v0 = qw - kv0;       // >= 0 (kv0 <= qw here)
            int nkv2 = (v0 >> 5) + 1; if (nkv2 > 4) nkv2 = 4;
            const bool diag = (kv0 + 127 > qw);

            // S^T = K . Q (raw scores; scale folded into Q)
            f32x16v st[4];
            __builtin_amdgcn_s_setprio(1);
            #pragma unroll
            for (int kv2 = 0; kv2 < 4; ++kv2) {
                if (kv2 < nkv2) {
                    f32x16v a = {};
                    #pragma unroll
                    for (int kf = 0; kf < 4; ++kf) {
                        u16x8 ka = *(const u16x8*)&Kl[cur][(kv2 * 32 + l31) * 64 +
                                                           (((kf * 2 + hi) ^ (l31 & 7)) * 8)];
                        a = mfma32(ka, qf[kf], a);
                    }
                    st[kv2] = a;
                } else {
                    st[kv2] = (f32x16v)(-1e30f);
                }
            }
            __builtin_amdgcn_s_setprio(0);

            // causal mask on raw scores (diagonal tile only)
            if (diag) {
                #pragma unroll
                for (int kv2 = 0; kv2 < 4; ++kv2) {
                    if (kv2 < nkv2) {
                        #pragma unroll
                        for (int r = 0; r < 16; ++r) {
                            int kv = kv0 + kv2 * 32 + (r & 3) + 8 * (r >> 2) + 4 * hi;
                            if (kv > qg) st[kv2][r] = -1e30f;
                        }
                    }
                }
            }

            // raw-score row max (in-lane tree + cross-half swap)
            float t16[16];
            #pragma unroll
            for (int i = 0; i < 16; ++i)
                t16[i] = fmaxf(fmaxf(st[0][i], st[1][i]), fmaxf(st[2][i], st[3][i]));
            #pragma unroll
            for (int i = 0; i < 8; ++i) t16[i] = fmaxf(t16[i], t16[i + 8]);
            #pragma unroll
            for (int i = 0; i < 4; ++i) t16[i] = fmaxf(t16[i], t16[i + 4]);
            float rm = fmaxf(fmaxf(t16[0], t16[1]), fmaxf(t16[2], t16[3]));
            rm = fmaxf(rm, __shfl_xor(rm, 32, 64));

            // upper bound on biased max: raw max + largest in-tile bias
            int kvmax = kv0 + 127; if (kvmax > qw + 31) kvmax = qw + 31;
            float cand = rm + slope2 * (float)(kvmax - 2047);

            // defer-max: rescale only when the bound moved by > 8
            if (!__all(cand - m_r <= 8.0f)) {
                float mn = fmaxf(m_r, cand);
                float alpha = exp2f(m_r - mn);
                m_r = mn;
                l_r *= alpha;
                Ot[0] *= alpha;
                Ot[1] *= alpha;
            }

            // per-kv2: exp2 (bias fused), partial sum, pack to bf16 (st dies)
            unsigned pku[4][8];
            float s16[16] = {};
            #pragma unroll
            for (int kv2 = 0; kv2 < 4; ++kv2) {
                if (kv2 < nkv2) {
                    float base2 = slope2 * (float)(kv0 + kv2 * 32 + 4 * hi - 2047) - m_r;
                    #pragma unroll
                    for (int r = 0; r < 16; ++r) {
                        float koff = (float)((r & 3) + 8 * (r >> 2));
                        st[kv2][r] = exp2f(st[kv2][r] + fmaf(slope2, koff, base2));
                        s16[r] += st[kv2][r];
                    }
                    #pragma unroll
                    for (int idx = 0; idx < 8; ++idx) {
                        unsigned lo2 = __builtin_bit_cast(unsigned short, (__bf16)st[kv2][2 * idx]);
                        unsigned hh = __builtin_bit_cast(unsigned short, (__bf16)st[kv2][2 * idx + 1]);
                        pku[kv2][idx] = lo2 | (hh << 16);
                    }
                }
            }
            #pragma unroll
            for (int i = 0; i < 8; ++i) s16[i] += s16[i + 8];
            #pragma unroll
            for (int i = 0; i < 4; ++i) s16[i] += s16[i + 4];
            float rs = (s16[0] + s16[1]) + (s16[2] + s16[3]);
            rs += __shfl_xor(rs, 32, 64);
            l_r += rs;

            // O^T += V^T . P^T (skip masked kf pairs)
            __builtin_amdgcn_s_setprio(1);
            #pragma unroll
            for (int kf = 0; kf < 8; ++kf) {
                if ((kf >> 1) < nkv2) {
                    const int kv2 = kf >> 1, base = 4 * (kf & 1);
                    unsigned s0 = hi ? pku[kv2][base + 0] : pku[kv2][base + 2];
                    unsigned s1 = hi ? pku[kv2][base + 1] : pku[kv2][base + 3];
                    unsigned r0 = __shfl_xor(s0, 32, 64);
                    unsigned r1 = __shfl_xor(s1, 32, 64);
                    u32x4 w;
                    w[0] = hi ? r0 : pku[kv2][base + 0];
                    w[1] = hi ? r1 : pku[kv2][base + 1];
                    w[2] = hi ? pku[kv2][base + 2] : r0;
                    w[3] = hi ? pku[kv2][base + 3] : r1;
                    u16x8 pb = __builtin_bit_cast(u16x8, w);
                    #pragma unroll
                    for (int dn = 0; dn < 2; ++dn) {
                        u16x8 va = *(const u16x8*)&Vl[cur][(dn * 32 + l31) * 128 +
                                                           (((kf * 2 + hi) ^ (l31 & 15)) * 8)];
                        Ot[dn] = mfma32(va, pb, Ot[dn]);
                    }
                }
            }
            __builtin_amdgcn_s_setprio(0);
        }

        cur ^= 1;
    }

    // epilogue: normalize, write bf16 [B*T][C]; r-quads give contiguous d
    float rl = 1.0f / l_r;
    #pragma unroll
    for (int dn = 0; dn < 2; ++dn)
        #pragma unroll
        for (int rq = 0; rq < 4; ++rq) {
            u16x4 o;
            #pragma unroll
            for (int jj = 0; jj < 4; ++jj)
                o[jj] = f2bf(Ot[dn][rq * 4 + jj] * rl);
            int d = dn * 32 + 8 * rq + 4 * hi;
            *(u16x4*)&aout[(b * 2048 + qg) * 1024 + h * 64 + d] = o;
        }
#undef STAGE
}

// ---------------------------------------------------------------------------
extern "C" void kernel_launch(void* const* d_in, const int* in_sizes, int n_in,
                              void* d_out, int out_size, void* d_ws, size_t ws_size,
                              hipStream_t stream)
{
    const float* x  = (const float*)d_in[0];
    const float* Wq = (const float*)d_in[1];
    const float* Wk = (const float*)d_in[2];
    const float* Wv = (const float*)d_in[3];
    const float* Wo = (const float*)d_in[4];

    unsigned short* ws = (unsigned short*)d_ws;
    unsigned short* wb = ws;                       // 4 x 1M bf16 (W^T: q,k,v,o)
    unsigned short* xb = ws + 4194304;             // 8M bf16
    unsigned short* qh = ws + 12582912;
    unsigned short* kh = qh + 8388608;
    unsigned short* vt = kh + 8388608;
    unsigned short* ao = xb;                       // alias: xb dead after QKV GEMM

    castx<<<dim3(8192), dim3(256), 0, stream>>>(x, xb);
    wtcast<<<dim3(16, 16, 4), dim3(256), 0, stream>>>(Wq, Wk, Wv, Wo, wb);
    gemm_gl<0><<<dim3(8, 64, 3), dim3(256), 0, stream>>>(xb, wb, qh, (float*)nullptr);
    attn8s<<<dim3(8, 64), dim3(512), 0, stream>>>(qh, kh, vt, ao);
    gemm_gl<1><<<dim3(8, 64, 1), dim3(256), 0, stream>>>(
        ao, wb + 3 * 1048576, (unsigned short*)nullptr, (float*)d_out);
}

// Round 17
// 213.543 us; speedup vs baseline: 1.1098x; 1.0787x over previous
//
#include <hip/hip_runtime.h>
#include <hip/hip_bf16.h>

// Problem constants: B=4, T=2048, C=1024, NH=16, HD=64
#define TSEQ   2048
#define CDIM   1024
#define NHEAD  16
#define HDIM   64

typedef float f32x4  __attribute__((ext_vector_type(4)));
typedef float f32x16v __attribute__((ext_vector_type(16)));
typedef __bf16 bf16x8 __attribute__((ext_vector_type(8)));
typedef unsigned short u16x8 __attribute__((ext_vector_type(8)));
typedef unsigned short u16x4 __attribute__((ext_vector_type(4)));
typedef unsigned int   u32x4 __attribute__((ext_vector_type(4)));

#define QSCALE 0.18033688011112042f   // 0.125 * log2(e)
#define LOG2E  1.4426950408889634f

static __device__ __forceinline__ unsigned short f2bf(float f) {
    unsigned u = __builtin_bit_cast(unsigned, f);
    unsigned r = u + 0x7FFFu + ((u >> 16) & 1u);   // round-to-nearest-even
    return (unsigned short)(r >> 16);
}

static __device__ __forceinline__ f32x4 mfma16(u16x8 a, u16x8 b, f32x4 c) {
    return __builtin_amdgcn_mfma_f32_16x16x32_bf16(
        __builtin_bit_cast(bf16x8, a), __builtin_bit_cast(bf16x8, b), c, 0, 0, 0);
}
static __device__ __forceinline__ f32x16v mfma32(u16x8 a, u16x8 b, f32x16v c) {
    return __builtin_amdgcn_mfma_f32_32x32x16_bf16(
        __builtin_bit_cast(bf16x8, a), __builtin_bit_cast(bf16x8, b), c, 0, 0, 0);
}

static __device__ __forceinline__ void gload16(const void* g, void* l) {
    __builtin_amdgcn_global_load_lds(
        (const __attribute__((address_space(1))) unsigned int*)g,
        (__attribute__((address_space(3))) unsigned int*)l, 16, 0, 0);
}

// Workspace layout (u16 units):
//   wb : 0        .. 4194303   (W^T q,k,v,o bf16, 1M each -- TRANSPOSED [n][k])
//   xb : 4194304  .. 12582911  (x bf16, 8M) -- reused as `ao` after QKV GEMM
//   qh : 12582912 .. 20971519  ([B,NH,T,HD] bf16, pre-scaled by QSCALE)
//   kh : 20971520 .. 29359103  ([B,NH,T,HD] bf16)
//   vt : 29359104 .. 37748735  ([B,NH,HD,T] bf16 -- V TRANSPOSED)

// ---------------------------------------------------------------------------
__global__ __launch_bounds__(256) void castx(
    const float* __restrict__ x, unsigned short* __restrict__ xb)
{
    int t = blockIdx.x * 256 + threadIdx.x;   // float4 index, < 2097152
    f32x4 v = *(const f32x4*)&x[t * 4];
    u16x4 o;
    o[0] = f2bf(v[0]); o[1] = f2bf(v[1]); o[2] = f2bf(v[2]); o[3] = f2bf(v[3]);
    *(u16x4*)&xb[t * 4] = o;
}

// ---------------------------------------------------------------------------
__global__ __launch_bounds__(256) void wtcast(
    const float* __restrict__ wq, const float* __restrict__ wk,
    const float* __restrict__ wv, const float* __restrict__ wo,
    unsigned short* __restrict__ wt)
{
    __shared__ unsigned short t[64 * 72];
    const int z = blockIdx.z;
    const float* src = (z == 0) ? wq : (z == 1) ? wk : (z == 2) ? wv : wo;
    const int k0 = blockIdx.x * 64, n0 = blockIdx.y * 64, tid = threadIdx.x;

    #pragma unroll
    for (int i = 0; i < 4; ++i) {
        int idx = i * 256 + tid;
        int r = idx >> 4, c4 = idx & 15;
        f32x4 v = *(const f32x4*)&src[(k0 + r) * 1024 + n0 + c4 * 4];
        u16x4 o;
        o[0] = f2bf(v[0]); o[1] = f2bf(v[1]); o[2] = f2bf(v[2]); o[3] = f2bf(v[3]);
        *(u16x4*)&t[r * 72 + c4 * 4] = o;
    }
    __syncthreads();
    #pragma unroll
    for (int i = 0; i < 2; ++i) {
        int idx = i * 256 + tid;
        int n = idx >> 3, k8 = idx & 7;
        u16x8 o;
        #pragma unroll
        for (int e = 0; e < 8; ++e) o[e] = t[(k8 * 8 + e) * 72 + n];
        *(u16x8*)&wt[z * 1048576 + (n0 + n) * 1024 + k0 + k8 * 8] = o;
    }
}

// ---------------------------------------------------------------------------
// Kernel 2/4: 128x128 bf16 GEMM, BK=64, global_load_lds staging with
// XOR bank-conflict swizzle (G4 fix, same pattern as attn's K staging):
// source chunk kgc = (lane&7)^krow (linear LDS dest, rule 21); fragment
// reads use physical chunk (ks*4 + (lane>>4)) ^ (lrow&7). Without this the
// [128][64] bf16 tile (128B rows = 32-dword stride) is a ~16-way conflict
// on every ds_read_b128 (measured 1.9e7 conflict cycles, r16).
// MODE 0: z = q/k/v. q scaled by QSCALE; v written transposed [bh][d][t].
// MODE 1: fp32 row-major to d_out.
// ---------------------------------------------------------------------------
template<int MODE>
__global__ __launch_bounds__(256) void gemm_gl(
    const unsigned short* __restrict__ A, const unsigned short* __restrict__ WT,
    unsigned short* __restrict__ outb, float* __restrict__ outf)
{
    __shared__ __align__(16) unsigned short Al[128 * 64];
    __shared__ __align__(16) unsigned short Bl[128 * 64];

    const int tid  = threadIdx.x;
    const int z    = blockIdx.z;
    const int m0   = blockIdx.y * 128;
    const int n0   = blockIdx.x * 128;
    const unsigned short* W = WT + (MODE == 0 ? z * 1048576 : 0);

    const int wid  = tid >> 6, lane = tid & 63;
    const int wr   = (wid >> 1) * 64, wc = (wid & 1) * 64;
    const int lrow = lane & 15;
    const int g4   = lane >> 4;            // 16-lane group = col-chunk
    const int krow = lane >> 3;            // staging: row within 8-row chunk
    const int kgc  = (lane & 7) ^ krow;    // staging: swizzled source chunk

    f32x4 acc[4][4] = {};

    for (int kt = 0; kt < 16; ++kt) {
        __syncthreads();
        #pragma unroll
        for (int c = 0; c < 4; ++c) {
            int cz = wid * 4 + c;
            int row = cz * 8 + krow;
            gload16(&A[(m0 + row) * 1024 + kt * 64 + kgc * 8], &Al[cz * 512]);
            gload16(&W[(n0 + row) * 1024 + kt * 64 + kgc * 8], &Bl[cz * 512]);
        }
        __syncthreads();
        #pragma unroll
        for (int ks = 0; ks < 2; ++ks) {
            const int pch = ((ks * 4 + g4) ^ (lrow & 7)) * 8;   // swizzled read
            u16x8 af[4], bfr[4];
            #pragma unroll
            for (int m = 0; m < 4; ++m)
                af[m] = *(const u16x8*)&Al[(wr + m * 16 + lrow) * 64 + pch];
            #pragma unroll
            for (int n = 0; n < 4; ++n)
                bfr[n] = *(const u16x8*)&Bl[(wc + n * 16 + lrow) * 64 + pch];
            #pragma unroll
            for (int m = 0; m < 4; ++m)
                #pragma unroll
                for (int n = 0; n < 4; ++n)
                    acc[m][n] = mfma16(af[m], bfr[n], acc[m][n]);
        }
    }

    const int g = lane >> 4;
    #pragma unroll
    for (int m = 0; m < 4; ++m)
        #pragma unroll
        for (int n = 0; n < 4; ++n)
            #pragma unroll
            for (int j = 0; j < 4; ++j) {
                int grow = m0 + wr + m * 16 + g * 4 + j;
                int gcol = n0 + wc + n * 16 + lrow;
                float val = acc[m][n][j];
                if (MODE == 0) {
                    int b = grow >> 11, t = grow & 2047;
                    int h = gcol >> 6,  d = gcol & 63;
                    if (z == 0) val *= QSCALE;
                    if (z == 2)
                        outb[z * 8388608 + (((b << 4) + h) * 64 + d) * 2048 + t] = f2bf(val);
                    else
                        outb[z * 8388608 + (((b << 4) + h) * 2048 + t) * 64 + d] = f2bf(val);
                } else {
                    outf[grow * 1024 + gcol] = val;
                }
            }
}

// ---------------------------------------------------------------------------
// Kernel 3: 8-wave single-chunk flash attention (r14 best config, verbatim).
// Grid (8,64) = 512 blocks; c = (bh<32 ? 7-x : x). KVBLK=128 dbuf (64KB LDS),
// XOR-swizzled global_load_lds, swapped QK^T 32x32, raw-max bound, fused
// bias-exp2, defer-max, nkv2 diag skip, per-wave ALiBi window gates,
// windowed staging start. launch_bounds(512,2) caps VGPR at 128.
// ---------------------------------------------------------------------------
__global__ __launch_bounds__(512, 2) void attn8s(
    const unsigned short* __restrict__ qh, const unsigned short* __restrict__ kh,
    const unsigned short* __restrict__ vt, unsigned short* __restrict__ aout)
{
    __shared__ __align__(16) unsigned short Kl[2][128 * 64];
    __shared__ __align__(16) unsigned short Vl[2][64 * 128];

    const int bh  = blockIdx.y;
    const int h   = bh & 15, b = bh >> 4;
    const int c   = (bh < 32) ? (7 - (int)blockIdx.x) : (int)blockIdx.x;
    const int tid = threadIdx.x, wid = tid >> 6, lane = tid & 63;
    const int l31 = lane & 31, hi = lane >> 5;

    const unsigned short* Qb = qh + bh * (TSEQ * HDIM);
    const unsigned short* Kb = kh + bh * (TSEQ * HDIM);
    const unsigned short* Vb = vt + bh * (TSEQ * HDIM);  // [d][t]

    const float slope2 = exp2f(-0.5f * (float)(h + 1)) * LOG2E;
    const int   Wwin   = (int)ceilf(40.0f / slope2);     // ALiBi window

    // block tile range: windowed start .. diagonal tile of top wave
    int blo = c * 256 - Wwin;
    const int t0     = (blo > 0) ? (blo >> 7) : 0;
    const int t_last = 2 * c + 1;

    const int qw = c * 256 + wid * 32;     // wave's first q row
    const int qg = qw + l31;               // lane's q row

    // staging lane constants (source-side XOR swizzle, LDS dest linear)
    const int krow = lane >> 3;            // K: row within 8-row chunk
    const int kgc  = (lane & 7) ^ krow;    // K: swizzled 16B chunk
    const int vrow = lane >> 4;            // V: d-row within 4-row chunk
    const int vcc  = lane & 15;

#define STAGE(BUF, KV) do {                                                   \
    _Pragma("unroll")                                                         \
    for (int i_ = 0; i_ < 2; ++i_) {                                          \
        int cz_ = wid * 2 + i_;                       /* 0..15 */             \
        gload16(&Kb[((KV) + cz_ * 8 + krow) * 64 + kgc * 8],                  \
                &Kl[BUF][cz_ * 512]);                                         \
        int d_ = cz_ * 4 + vrow;                                              \
        int gc_ = vcc ^ (d_ & 15);                                            \
        gload16(&Vb[d_ * 2048 + (KV) + gc_ * 8], &Vl[BUF][cz_ * 512]);        \
    } } while (0)

    // Q B-frags: col = l31 -> q row, k = kf*16 + hi*8 + i (pre-scaled)
    u16x8 qf[4];
    #pragma unroll
    for (int kf = 0; kf < 4; ++kf)
        qf[kf] = *(const u16x8*)&Qb[qg * 64 + kf * 16 + hi * 8];
    float m_r = -1e30f, l_r = 0.f;
    f32x16v Ot[2] = {};                    // O^T: d = dn*32+(r&3)+8*(r>>2)+4*hi

    STAGE(0, t0 * 128);                    // prologue
    int cur = 0;

    for (int t = t0; t <= t_last; ++t) {
        const int kv0 = t * 128;
        __syncthreads();                   // drains this tile's loads

        if (t < t_last) STAGE(cur ^ 1, (t + 1) * 128);

        // wave-level gates: causal top + ALiBi window bottom
        if (kv0 <= qw + 31 && kv0 + 127 >= qw - Wwin) {
            const int v0 = qw - kv0;       // >= 0 (kv0 <= qw here)
            int nkv2 = (v0 >> 5) + 1; if (nkv2 > 4) nkv2 = 4;
            const bool diag = (kv0 + 127 > qw);

            // S^T = K . Q (raw scores; scale folded into Q)
            f32x16v st[4];
            __builtin_amdgcn_s_setprio(1);
            #pragma unroll
            for (int kv2 = 0; kv2 < 4; ++kv2) {
                if (kv2 < nkv2) {
                    f32x16v a = {};
                    #pragma unroll
                    for (int kf = 0; kf < 4; ++kf) {
                        u16x8 ka = *(const u16x8*)&Kl[cur][(kv2 * 32 + l31) * 64 +
                                                           (((kf * 2 + hi) ^ (l31 & 7)) * 8)];
                        a = mfma32(ka, qf[kf], a);
                    }
                    st[kv2] = a;
                } else {
                    st[kv2] = (f32x16v)(-1e30f);
                }
            }
            __builtin_amdgcn_s_setprio(0);

            // causal mask on raw scores (diagonal tile only)
            if (diag) {
                #pragma unroll
                for (int kv2 = 0; kv2 < 4; ++kv2) {
                    if (kv2 < nkv2) {
                        #pragma unroll
                        for (int r = 0; r < 16; ++r) {
                            int kv = kv0 + kv2 * 32 + (r & 3) + 8 * (r >> 2) + 4 * hi;
                            if (kv > qg) st[kv2][r] = -1e30f;
                        }
                    }
                }
            }

            // raw-score row max (in-lane tree + cross-half swap)
            float t16[16];
            #pragma unroll
            for (int i = 0; i < 16; ++i)
                t16[i] = fmaxf(fmaxf(st[0][i], st[1][i]), fmaxf(st[2][i], st[3][i]));
            #pragma unroll
            for (int i = 0; i < 8; ++i) t16[i] = fmaxf(t16[i], t16[i + 8]);
            #pragma unroll
            for (int i = 0; i < 4; ++i) t16[i] = fmaxf(t16[i], t16[i + 4]);
            float rm = fmaxf(fmaxf(t16[0], t16[1]), fmaxf(t16[2], t16[3]));
            rm = fmaxf(rm, __shfl_xor(rm, 32, 64));

            // upper bound on biased max: raw max + largest in-tile bias
            int kvmax = kv0 + 127; if (kvmax > qw + 31) kvmax = qw + 31;
            float cand = rm + slope2 * (float)(kvmax - 2047);

            // defer-max: rescale only when the bound moved by > 8
            if (!__all(cand - m_r <= 8.0f)) {
                float mn = fmaxf(m_r, cand);
                float alpha = exp2f(m_r - mn);
                m_r = mn;
                l_r *= alpha;
                Ot[0] *= alpha;
                Ot[1] *= alpha;
            }

            // per-kv2: exp2 (bias fused), partial sum, pack to bf16 (st dies)
            unsigned pku[4][8];
            float s16[16] = {};
            #pragma unroll
            for (int kv2 = 0; kv2 < 4; ++kv2) {
                if (kv2 < nkv2) {
                    float base2 = slope2 * (float)(kv0 + kv2 * 32 + 4 * hi - 2047) - m_r;
                    #pragma unroll
                    for (int r = 0; r < 16; ++r) {
                        float koff = (float)((r & 3) + 8 * (r >> 2));
                        st[kv2][r] = exp2f(st[kv2][r] + fmaf(slope2, koff, base2));
                        s16[r] += st[kv2][r];
                    }
                    #pragma unroll
                    for (int idx = 0; idx < 8; ++idx) {
                        unsigned lo2 = __builtin_bit_cast(unsigned short, (__bf16)st[kv2][2 * idx]);
                        unsigned hh = __builtin_bit_cast(unsigned short, (__bf16)st[kv2][2 * idx + 1]);
                        pku[kv2][idx] = lo2 | (hh << 16);
                    }
                }
            }
            #pragma unroll
            for (int i = 0; i < 8; ++i) s16[i] += s16[i + 8];
            #pragma unroll
            for (int i = 0; i < 4; ++i) s16[i] += s16[i + 4];
            float rs = (s16[0] + s16[1]) + (s16[2] + s16[3]);
            rs += __shfl_xor(rs, 32, 64);
            l_r += rs;

            // O^T += V^T . P^T (skip masked kf pairs)
            __builtin_amdgcn_s_setprio(1);
            #pragma unroll
            for (int kf = 0; kf < 8; ++kf) {
                if ((kf >> 1) < nkv2) {
                    const int kv2 = kf >> 1, base = 4 * (kf & 1);
                    unsigned s0 = hi ? pku[kv2][base + 0] : pku[kv2][base + 2];
                    unsigned s1 = hi ? pku[kv2][base + 1] : pku[kv2][base + 3];
                    unsigned r0 = __shfl_xor(s0, 32, 64);
                    unsigned r1 = __shfl_xor(s1, 32, 64);
                    u32x4 w;
                    w[0] = hi ? r0 : pku[kv2][base + 0];
                    w[1] = hi ? r1 : pku[kv2][base + 1];
                    w[2] = hi ? pku[kv2][base + 2] : r0;
                    w[3] = hi ? pku[kv2][base + 3] : r1;
                    u16x8 pb = __builtin_bit_cast(u16x8, w);
                    #pragma unroll
                    for (int dn = 0; dn < 2; ++dn) {
                        u16x8 va = *(const u16x8*)&Vl[cur][(dn * 32 + l31) * 128 +
                                                           (((kf * 2 + hi) ^ (l31 & 15)) * 8)];
                        Ot[dn] = mfma32(va, pb, Ot[dn]);
                    }
                }
            }
            __builtin_amdgcn_s_setprio(0);
        }

        cur ^= 1;
    }

    // epilogue: normalize, write bf16 [B*T][C]; r-quads give contiguous d
    float rl = 1.0f / l_r;
    #pragma unroll
    for (int dn = 0; dn < 2; ++dn)
        #pragma unroll
        for (int rq = 0; rq < 4; ++rq) {
            u16x4 o;
            #pragma unroll
            for (int jj = 0; jj < 4; ++jj)
                o[jj] = f2bf(Ot[dn][rq * 4 + jj] * rl);
            int d = dn * 32 + 8 * rq + 4 * hi;
            *(u16x4*)&aout[(b * 2048 + qg) * 1024 + h * 64 + d] = o;
        }
#undef STAGE
}

// ---------------------------------------------------------------------------
extern "C" void kernel_launch(void* const* d_in, const int* in_sizes, int n_in,
                              void* d_out, int out_size, void* d_ws, size_t ws_size,
                              hipStream_t stream)
{
    const float* x  = (const float*)d_in[0];
    const float* Wq = (const float*)d_in[1];
    const float* Wk = (const float*)d_in[2];
    const float* Wv = (const float*)d_in[3];
    const float* Wo = (const float*)d_in[4];

    unsigned short* ws = (unsigned short*)d_ws;
    unsigned short* wb = ws;                       // 4 x 1M bf16 (W^T: q,k,v,o)
    unsigned short* xb = ws + 4194304;             // 8M bf16
    unsigned short* qh = ws + 12582912;
    unsigned short* kh = qh + 8388608;
    unsigned short* vt = kh + 8388608;
    unsigned short* ao = xb;                       // alias: xb dead after QKV GEMM

    castx<<<dim3(8192), dim3(256), 0, stream>>>(x, xb);
    wtcast<<<dim3(16, 16, 4), dim3(256), 0, stream>>>(Wq, Wk, Wv, Wo, wb);
    gemm_gl<0><<<dim3(8, 64, 3), dim3(256), 0, stream>>>(xb, wb, qh, (float*)nullptr);
    attn8s<<<dim3(8, 64), dim3(512), 0, stream>>>(qh, kh, vt, ao);
    gemm_gl<1><<<dim3(8, 64, 1), dim3(256), 0, stream>>>(
        ao, wb + 3 * 1048576, (unsigned short*)nullptr, (float*)d_out);
}

// Round 19
// 209.375 us; speedup vs baseline: 1.1319x; 1.0199x over previous
//
#include <hip/hip_runtime.h>
#include <hip/hip_bf16.h>

// Problem constants: B=4, T=2048, C=1024, NH=16, HD=64
#define TSEQ   2048
#define CDIM   1024
#define NHEAD  16
#define HDIM   64

typedef float f32x4  __attribute__((ext_vector_type(4)));
typedef float f32x16v __attribute__((ext_vector_type(16)));
typedef __bf16 bf16x8 __attribute__((ext_vector_type(8)));
typedef unsigned short u16x8 __attribute__((ext_vector_type(8)));
typedef unsigned short u16x4 __attribute__((ext_vector_type(4)));
typedef unsigned int   u32x4 __attribute__((ext_vector_type(4)));
typedef unsigned int   u32x2 __attribute__((ext_vector_type(2)));

#define QSCALE 0.18033688011112042f   // 0.125 * log2(e)
#define LOG2E  1.4426950408889634f

static __device__ __forceinline__ unsigned short f2bf(float f) {
    unsigned u = __builtin_bit_cast(unsigned, f);
    unsigned r = u + 0x7FFFu + ((u >> 16) & 1u);   // round-to-nearest-even
    return (unsigned short)(r >> 16);
}

static __device__ __forceinline__ f32x4 mfma16(u16x8 a, u16x8 b, f32x4 c) {
    return __builtin_amdgcn_mfma_f32_16x16x32_bf16(
        __builtin_bit_cast(bf16x8, a), __builtin_bit_cast(bf16x8, b), c, 0, 0, 0);
}
static __device__ __forceinline__ f32x16v mfma32(u16x8 a, u16x8 b, f32x16v c) {
    return __builtin_amdgcn_mfma_f32_32x32x16_bf16(
        __builtin_bit_cast(bf16x8, a), __builtin_bit_cast(bf16x8, b), c, 0, 0, 0);
}

static __device__ __forceinline__ void gload16(const void* g, void* l) {
    __builtin_amdgcn_global_load_lds(
        (const __attribute__((address_space(1))) unsigned int*)g,
        (__attribute__((address_space(3))) unsigned int*)l, 16, 0, 0);
}

// permlane32_swap via the documented builtin (compiler models regs+hazards):
// returns r[0] = {a.lanes0-31, b.lanes0-31}, r[1] = {a.lanes32-63, b.lanes32-63}
static __device__ __forceinline__ void plswap2(unsigned &a, unsigned &b) {
    u32x2 r = __builtin_amdgcn_permlane32_swap(a, b, false, false);
    a = r[0];
    b = r[1];
}

// Workspace layout (u16 units):
//   wb : 0        .. 4194303   (W^T q,k,v,o bf16, 1M each -- TRANSPOSED [n][k])
//   xb : 4194304  .. 12582911  (x bf16, 8M) -- reused as `ao` after QKV GEMM
//   qh : 12582912 .. 20971519  ([B,NH,T,HD] bf16, pre-scaled by QSCALE)
//   kh : 20971520 .. 29359103  ([B,NH,T,HD] bf16)
//   vt : 29359104 .. 37748735  ([B,NH,HD,T] bf16 -- V TRANSPOSED)

// ---------------------------------------------------------------------------
__global__ __launch_bounds__(256) void castx(
    const float* __restrict__ x, unsigned short* __restrict__ xb)
{
    int t = blockIdx.x * 256 + threadIdx.x;   // float4 index, < 2097152
    f32x4 v = *(const f32x4*)&x[t * 4];
    u16x4 o;
    o[0] = f2bf(v[0]); o[1] = f2bf(v[1]); o[2] = f2bf(v[2]); o[3] = f2bf(v[3]);
    *(u16x4*)&xb[t * 4] = o;
}

// ---------------------------------------------------------------------------
__global__ __launch_bounds__(256) void wtcast(
    const float* __restrict__ wq, const float* __restrict__ wk,
    const float* __restrict__ wv, const float* __restrict__ wo,
    unsigned short* __restrict__ wt)
{
    __shared__ unsigned short t[64 * 72];
    const int z = blockIdx.z;
    const float* src = (z == 0) ? wq : (z == 1) ? wk : (z == 2) ? wv : wo;
    const int k0 = blockIdx.x * 64, n0 = blockIdx.y * 64, tid = threadIdx.x;

    #pragma unroll
    for (int i = 0; i < 4; ++i) {
        int idx = i * 256 + tid;
        int r = idx >> 4, c4 = idx & 15;
        f32x4 v = *(const f32x4*)&src[(k0 + r) * 1024 + n0 + c4 * 4];
        u16x4 o;
        o[0] = f2bf(v[0]); o[1] = f2bf(v[1]); o[2] = f2bf(v[2]); o[3] = f2bf(v[3]);
        *(u16x4*)&t[r * 72 + c4 * 4] = o;
    }
    __syncthreads();
    #pragma unroll
    for (int i = 0; i < 2; ++i) {
        int idx = i * 256 + tid;
        int n = idx >> 3, k8 = idx & 7;
        u16x8 o;
        #pragma unroll
        for (int e = 0; e < 8; ++e) o[e] = t[(k8 * 8 + e) * 72 + n];
        *(u16x8*)&wt[z * 1048576 + (n0 + n) * 1024 + k0 + k8 * 8] = o;
    }
}

// ---------------------------------------------------------------------------
// Kernel 2/4: 128x128 bf16 GEMM, BK=64, global_load_lds staging with
// XOR bank-conflict swizzle (r17-proven: conflicts 1.9e7 -> gone, -26 us).
// MODE 0: z = q/k/v. q scaled by QSCALE; v written transposed [bh][d][t].
// MODE 1: fp32 row-major to d_out.
// ---------------------------------------------------------------------------
template<int MODE>
__global__ __launch_bounds__(256) void gemm_gl(
    const unsigned short* __restrict__ A, const unsigned short* __restrict__ WT,
    unsigned short* __restrict__ outb, float* __restrict__ outf)
{
    __shared__ __align__(16) unsigned short Al[128 * 64];
    __shared__ __align__(16) unsigned short Bl[128 * 64];

    const int tid  = threadIdx.x;
    const int z    = blockIdx.z;
    const int m0   = blockIdx.y * 128;
    const int n0   = blockIdx.x * 128;
    const unsigned short* W = WT + (MODE == 0 ? z * 1048576 : 0);

    const int wid  = tid >> 6, lane = tid & 63;
    const int wr   = (wid >> 1) * 64, wc = (wid & 1) * 64;
    const int lrow = lane & 15;
    const int g4   = lane >> 4;            // 16-lane group = col-chunk
    const int krow = lane >> 3;            // staging: row within 8-row chunk
    const int kgc  = (lane & 7) ^ krow;    // staging: swizzled source chunk

    f32x4 acc[4][4] = {};

    for (int kt = 0; kt < 16; ++kt) {
        __syncthreads();
        #pragma unroll
        for (int c = 0; c < 4; ++c) {
            int cz = wid * 4 + c;
            int row = cz * 8 + krow;
            gload16(&A[(m0 + row) * 1024 + kt * 64 + kgc * 8], &Al[cz * 512]);
            gload16(&W[(n0 + row) * 1024 + kt * 64 + kgc * 8], &Bl[cz * 512]);
        }
        __syncthreads();
        #pragma unroll
        for (int ks = 0; ks < 2; ++ks) {
            const int pch = ((ks * 4 + g4) ^ (lrow & 7)) * 8;   // swizzled read
            u16x8 af[4], bfr[4];
            #pragma unroll
            for (int m = 0; m < 4; ++m)
                af[m] = *(const u16x8*)&Al[(wr + m * 16 + lrow) * 64 + pch];
            #pragma unroll
            for (int n = 0; n < 4; ++n)
                bfr[n] = *(const u16x8*)&Bl[(wc + n * 16 + lrow) * 64 + pch];
            #pragma unroll
            for (int m = 0; m < 4; ++m)
                #pragma unroll
                for (int n = 0; n < 4; ++n)
                    acc[m][n] = mfma16(af[m], bfr[n], acc[m][n]);
        }
    }

    const int g = lane >> 4;
    #pragma unroll
    for (int m = 0; m < 4; ++m)
        #pragma unroll
        for (int n = 0; n < 4; ++n)
            #pragma unroll
            for (int j = 0; j < 4; ++j) {
                int grow = m0 + wr + m * 16 + g * 4 + j;
                int gcol = n0 + wc + n * 16 + lrow;
                float val = acc[m][n][j];
                if (MODE == 0) {
                    int b = grow >> 11, t = grow & 2047;
                    int h = gcol >> 6,  d = gcol & 63;
                    if (z == 0) val *= QSCALE;
                    if (z == 2)
                        outb[z * 8388608 + (((b << 4) + h) * 64 + d) * 2048 + t] = f2bf(val);
                    else
                        outb[z * 8388608 + (((b << 4) + h) * 2048 + t) * 64 + d] = f2bf(val);
                } else {
                    outf[grow * 1024 + gcol] = val;
                }
            }
}

// ---------------------------------------------------------------------------
// Kernel 3: 8-wave single-chunk flash attention (r17 schedule). PV-fragment
// build uses __builtin_amdgcn_permlane32_swap (2 ops/kf, replaces
// 2 ds_bpermute + ~10 selects); reductions keep proven __shfl_xor.
// Grid (8,64); c = (bh<32?7-x:x). KVBLK=128 dbuf (64KB LDS), XOR-swizzled
// global_load_lds, swapped QK^T 32x32, raw-max bound, fused bias-exp2,
// defer-max, nkv2 diag skip, ALiBi window gates, windowed staging start.
// launch_bounds(512,2).
// ---------------------------------------------------------------------------
__global__ __launch_bounds__(512, 2) void attn8s(
    const unsigned short* __restrict__ qh, const unsigned short* __restrict__ kh,
    const unsigned short* __restrict__ vt, unsigned short* __restrict__ aout)
{
    __shared__ __align__(16) unsigned short Kl[2][128 * 64];
    __shared__ __align__(16) unsigned short Vl[2][64 * 128];

    const int bh  = blockIdx.y;
    const int h   = bh & 15, b = bh >> 4;
    const int c   = (bh < 32) ? (7 - (int)blockIdx.x) : (int)blockIdx.x;
    const int tid = threadIdx.x, wid = tid >> 6, lane = tid & 63;
    const int l31 = lane & 31, hi = lane >> 5;

    const unsigned short* Qb = qh + bh * (TSEQ * HDIM);
    const unsigned short* Kb = kh + bh * (TSEQ * HDIM);
    const unsigned short* Vb = vt + bh * (TSEQ * HDIM);  // [d][t]

    const float slope2 = exp2f(-0.5f * (float)(h + 1)) * LOG2E;
    const int   Wwin   = (int)ceilf(40.0f / slope2);     // ALiBi window

    // block tile range: windowed start .. diagonal tile of top wave
    int blo = c * 256 - Wwin;
    const int t0     = (blo > 0) ? (blo >> 7) : 0;
    const int t_last = 2 * c + 1;

    const int qw = c * 256 + wid * 32;     // wave's first q row
    const int qg = qw + l31;               // lane's q row

    // staging lane constants (source-side XOR swizzle, LDS dest linear)
    const int krow = lane >> 3;            // K: row within 8-row chunk
    const int kgc  = (lane & 7) ^ krow;    // K: swizzled 16B chunk
    const int vrow = lane >> 4;            // V: d-row within 4-row chunk
    const int vcc  = lane & 15;

#define STAGE(BUF, KV) do {                                                   \
    _Pragma("unroll")                                                         \
    for (int i_ = 0; i_ < 2; ++i_) {                                          \
        int cz_ = wid * 2 + i_;                       /* 0..15 */             \
        gload16(&Kb[((KV) + cz_ * 8 + krow) * 64 + kgc * 8],                  \
                &Kl[BUF][cz_ * 512]);                                         \
        int d_ = cz_ * 4 + vrow;                                              \
        int gc_ = vcc ^ (d_ & 15);                                            \
        gload16(&Vb[d_ * 2048 + (KV) + gc_ * 8], &Vl[BUF][cz_ * 512]);        \
    } } while (0)

    // Q B-frags: col = l31 -> q row, k = kf*16 + hi*8 + i (pre-scaled)
    u16x8 qf[4];
    #pragma unroll
    for (int kf = 0; kf < 4; ++kf)
        qf[kf] = *(const u16x8*)&Qb[qg * 64 + kf * 16 + hi * 8];
    float m_r = -1e30f, l_r = 0.f;
    f32x16v Ot[2] = {};                    // O^T: d = dn*32+(r&3)+8*(r>>2)+4*hi

    STAGE(0, t0 * 128);                    // prologue
    int cur = 0;

    for (int t = t0; t <= t_last; ++t) {
        const int kv0 = t * 128;
        __syncthreads();                   // drains this tile's loads

        if (t < t_last) STAGE(cur ^ 1, (t + 1) * 128);

        // wave-level gates: causal top + ALiBi window bottom
        if (kv0 <= qw + 31 && kv0 + 127 >= qw - Wwin) {
            const int v0 = qw - kv0;       // >= 0 (kv0 <= qw here)
            int nkv2 = (v0 >> 5) + 1; if (nkv2 > 4) nkv2 = 4;
            const bool diag = (kv0 + 127 > qw);

            // S^T = K . Q (raw scores; scale folded into Q)
            f32x16v st[4];
            __builtin_amdgcn_s_setprio(1);
            #pragma unroll
            for (int kv2 = 0; kv2 < 4; ++kv2) {
                if (kv2 < nkv2) {
                    f32x16v a = {};
                    #pragma unroll
                    for (int kf = 0; kf < 4; ++kf) {
                        u16x8 ka = *(const u16x8*)&Kl[cur][(kv2 * 32 + l31) * 64 +
                                                           (((kf * 2 + hi) ^ (l31 & 7)) * 8)];
                        a = mfma32(ka, qf[kf], a);
                    }
                    st[kv2] = a;
                } else {
                    st[kv2] = (f32x16v)(-1e30f);
                }
            }
            __builtin_amdgcn_s_setprio(0);

            // causal mask on raw scores (diagonal tile only)
            if (diag) {
                #pragma unroll
                for (int kv2 = 0; kv2 < 4; ++kv2) {
                    if (kv2 < nkv2) {
                        #pragma unroll
                        for (int r = 0; r < 16; ++r) {
                            int kv = kv0 + kv2 * 32 + (r & 3) + 8 * (r >> 2) + 4 * hi;
                            if (kv > qg) st[kv2][r] = -1e30f;
                        }
                    }
                }
            }

            // raw-score row max (in-lane tree + cross-half swap)
            float t16[16];
            #pragma unroll
            for (int i = 0; i < 16; ++i)
                t16[i] = fmaxf(fmaxf(st[0][i], st[1][i]), fmaxf(st[2][i], st[3][i]));
            #pragma unroll
            for (int i = 0; i < 8; ++i) t16[i] = fmaxf(t16[i], t16[i + 8]);
            #pragma unroll
            for (int i = 0; i < 4; ++i) t16[i] = fmaxf(t16[i], t16[i + 4]);
            float rm = fmaxf(fmaxf(t16[0], t16[1]), fmaxf(t16[2], t16[3]));
            rm = fmaxf(rm, __shfl_xor(rm, 32, 64));

            // upper bound on biased max: raw max + largest in-tile bias
            int kvmax = kv0 + 127; if (kvmax > qw + 31) kvmax = qw + 31;
            float cand = rm + slope2 * (float)(kvmax - 2047);

            // defer-max: rescale only when the bound moved by > 8
            if (!__all(cand - m_r <= 8.0f)) {
                float mn = fmaxf(m_r, cand);
                float alpha = exp2f(m_r - mn);
                m_r = mn;
                l_r *= alpha;
                Ot[0] *= alpha;
                Ot[1] *= alpha;
            }

            // per-kv2: exp2 (bias fused), partial sum, pack to bf16 (st dies)
            unsigned pku[4][8];
            float s16[16] = {};
            #pragma unroll
            for (int kv2 = 0; kv2 < 4; ++kv2) {
                if (kv2 < nkv2) {
                    float base2 = slope2 * (float)(kv0 + kv2 * 32 + 4 * hi - 2047) - m_r;
                    #pragma unroll
                    for (int r = 0; r < 16; ++r) {
                        float koff = (float)((r & 3) + 8 * (r >> 2));
                        st[kv2][r] = exp2f(st[kv2][r] + fmaf(slope2, koff, base2));
                        s16[r] += st[kv2][r];
                    }
                    #pragma unroll
                    for (int idx = 0; idx < 8; ++idx) {
                        unsigned lo2 = __builtin_bit_cast(unsigned short, (__bf16)st[kv2][2 * idx]);
                        unsigned hh = __builtin_bit_cast(unsigned short, (__bf16)st[kv2][2 * idx + 1]);
                        pku[kv2][idx] = lo2 | (hh << 16);
                    }
                }
            }
            #pragma unroll
            for (int i = 0; i < 8; ++i) s16[i] += s16[i + 8];
            #pragma unroll
            for (int i = 0; i < 4; ++i) s16[i] += s16[i + 4];
            float rs = (s16[0] + s16[1]) + (s16[2] + s16[3]);
            rs += __shfl_xor(rs, 32, 64);
            l_r += rs;

            // O^T += V^T . P^T; PV B-frags via permlane32_swap builtin:
            // plswap2(pk0, pk2): pk0' = {pk0.lo, pk2.lo}, pk2' = {pk0.hi,
            // pk2.hi} -- exactly the r14/r17 select+shfl fragment layout.
            __builtin_amdgcn_s_setprio(1);
            #pragma unroll
            for (int kf = 0; kf < 8; ++kf) {
                if ((kf >> 1) < nkv2) {
                    const int kv2 = kf >> 1, base = 4 * (kf & 1);
                    unsigned w0 = pku[kv2][base + 0], w2 = pku[kv2][base + 2];
                    unsigned w1 = pku[kv2][base + 1], w3 = pku[kv2][base + 3];
                    plswap2(w0, w2);
                    plswap2(w1, w3);
                    u32x4 w;
                    w[0] = w0; w[1] = w1; w[2] = w2; w[3] = w3;
                    u16x8 pb = __builtin_bit_cast(u16x8, w);
                    #pragma unroll
                    for (int dn = 0; dn < 2; ++dn) {
                        u16x8 va = *(const u16x8*)&Vl[cur][(dn * 32 + l31) * 128 +
                                                           (((kf * 2 + hi) ^ (l31 & 15)) * 8)];
                        Ot[dn] = mfma32(va, pb, Ot[dn]);
                    }
                }
            }
            __builtin_amdgcn_s_setprio(0);
        }

        cur ^= 1;
    }

    // epilogue: normalize, write bf16 [B*T][C]; r-quads give contiguous d
    float rl = 1.0f / l_r;
    #pragma unroll
    for (int dn = 0; dn < 2; ++dn)
        #pragma unroll
        for (int rq = 0; rq < 4; ++rq) {
            u16x4 o;
            #pragma unroll
            for (int jj = 0; jj < 4; ++jj)
                o[jj] = f2bf(Ot[dn][rq * 4 + jj] * rl);
            int d = dn * 32 + 8 * rq + 4 * hi;
            *(u16x4*)&aout[(b * 2048 + qg) * 1024 + h * 64 + d] = o;
        }
#undef STAGE
}

// ---------------------------------------------------------------------------
extern "C" void kernel_launch(void* const* d_in, const int* in_sizes, int n_in,
                              void* d_out, int out_size, void* d_ws, size_t ws_size,
                              hipStream_t stream)
{
    const float* x  = (const float*)d_in[0];
    const float* Wq = (const float*)d_in[1];
    const float* Wk = (const float*)d_in[2];
    const float* Wv = (const float*)d_in[3];
    const float* Wo = (const float*)d_in[4];

    unsigned short* ws = (unsigned short*)d_ws;
    unsigned short* wb = ws;                       // 4 x 1M bf16 (W^T: q,k,v,o)
    unsigned short* xb = ws + 4194304;             // 8M bf16
    unsigned short* qh = ws + 12582912;
    unsigned short* kh = qh + 8388608;
    unsigned short* vt = kh + 8388608;
    unsigned short* ao = xb;                       // alias: xb dead after QKV GEMM

    castx<<<dim3(8192), dim3(256), 0, stream>>>(x, xb);
    wtcast<<<dim3(16, 16, 4), dim3(256), 0, stream>>>(Wq, Wk, Wv, Wo, wb);
    gemm_gl<0><<<dim3(8, 64, 3), dim3(256), 0, stream>>>(xb, wb, qh, (float*)nullptr);
    attn8s<<<dim3(8, 64), dim3(512), 0, stream>>>(qh, kh, vt, ao);
    gemm_gl<1><<<dim3(8, 64, 1), dim3(256), 0, stream>>>(
        ao, wb + 3 * 1048576, (unsigned short*)nullptr, (float*)d_out);
}